// Round 3
// baseline (30768.799 us; speedup 1.0000x reference)
//
#include <hip/hip_runtime.h>
#include <hip/hip_cooperative_groups.h>

namespace cg = cooperative_groups;

// BiRNN: B=128, S=512, E=512, H=1024, V=50000, C=2
// Persistent cooperative kernel: 256 blocks (1/CU), each owns one
// (chain, 16-col stripe) with full K. Weights LDS-resident (bf16 hi/lo,
// fragment order). 513 phases, one grid.sync() per phase.
// chain = layer*2+dir: 0:h0 fwd, 1:h0 bwd, 2:h1 fwd, 3:h1 bwd.

#define S_LEN 512

typedef short bf16x8 __attribute__((ext_vector_type(8)));
typedef float f32x4 __attribute__((ext_vector_type(4)));

__device__ __forceinline__ unsigned short f2bf(float f) {
    unsigned u = __float_as_uint(f);
    u += 0x7fff + ((u >> 16) & 1);
    return (unsigned short)(u >> 16);
}
__device__ __forceinline__ float bf2f(unsigned short h) {
    return __uint_as_float(((unsigned)h) << 16);
}
__device__ __forceinline__ f32x4 mfma16(bf16x8 a, bf16x8 b, f32x4 c) {
    return __builtin_amdgcn_mfma_f32_16x16x32_bf16(a, b, c, 0, 0, 0);
}

// bf16x3 product accumulate: a_hi*b_hi + a_hi*b_lo + a_lo*b_hi
__device__ __forceinline__ f32x4 triple(const unsigned short* wl, int KT16, int g,
                                        bf16x8 ah, bf16x8 al, f32x4 acc) {
    bf16x8 bh = *(const bf16x8*)(wl + g * 8);
    bf16x8 bl = *(const bf16x8*)(wl + KT16 + g * 8);
    acc = mfma16(ah, bh, acc);
    acc = mfma16(ah, bl, acc);
    acc = mfma16(al, bh, acc);
    return acc;
}

__device__ __forceinline__ void ld_e(const float* erow, int kk, bf16x8& ah, bf16x8& al) {
    float4 v0 = *(const float4*)(erow + kk);
    float4 v1 = *(const float4*)(erow + kk + 4);
    float vv[8] = {v0.x, v0.y, v0.z, v0.w, v1.x, v1.y, v1.z, v1.w};
    #pragma unroll
    for (int j = 0; j < 8; ++j) {
        unsigned short h = f2bf(vv[j]);
        ah[j] = (short)h;
        al[j] = (short)f2bf(vv[j] - bf2f(h));
    }
}

// ws layout (bytes):
//  Hws  : 16 slices [layer][dir][parity][hi/lo] x (128*1024) ushort = 4,194,304
//  Hfin : [2 dir][128][1024] f32 @ 4194304 (1 MB)
//  FC1  : [128][64] f32 @ 5242880

__global__ __launch_bounds__(512) void rnn_persistent(
    const int* __restrict__ x, const float* __restrict__ emb,
    const float* __restrict__ f0Wi, const float* __restrict__ f0Wh,
    const float* __restrict__ f1Wi, const float* __restrict__ f1Wh,
    const float* __restrict__ b0Wi, const float* __restrict__ b0Wh,
    const float* __restrict__ b1Wi, const float* __restrict__ b1Wh,
    const float* __restrict__ f0bi, const float* __restrict__ f0bh,
    const float* __restrict__ f1bi, const float* __restrict__ f1bh,
    const float* __restrict__ b0bi, const float* __restrict__ b0bh,
    const float* __restrict__ b1bi, const float* __restrict__ b1bh,
    unsigned short* __restrict__ Hws, float* __restrict__ Hfin)
{
    __shared__ unsigned short wlds[65536];   // 128 KiB: weights hi | lo, fragment order
    __shared__ int idxs[128];

    cg::grid_group grid = cg::this_grid();

    int bid = blockIdx.x, tid = threadIdx.x;
    int chain = bid >> 6;            // 0..3
    int layer = chain >> 1, dir = chain & 1;
    int stripe = bid & 63;
    int cstart = stripe * 16;

    const float *WA, *WB, *bA, *bB;
    int KA;
    if (layer == 0) {
        WA = dir ? b0Wi : f0Wi; WB = dir ? b0Wh : f0Wh;
        bA = dir ? b0bi : f0bi; bB = dir ? b0bh : f0bh;
        KA = 512;                    // E part
    } else {
        WA = dir ? b1Wi : f1Wi; WB = dir ? b1Wh : f1Wh;
        bA = dir ? b1bi : f1bi; bB = dir ? b1bh : f1bh;
        KA = 1024;                   // h0 part
    }
    const int Ktot = KA + 1024;
    const int KT16 = Ktot * 16;      // ushort offset of lo region

    // ---- one-time: weights -> LDS, fp32 -> bf16 hi/lo, fragment order ----
    {
        int colw = tid & 15, kb = tid >> 4;   // kb 0..31
        for (int k = kb; k < KA; k += 32) {
            float w = WA[(size_t)k * 1024 + cstart + colw];
            unsigned short h = f2bf(w);
            int o = ((k >> 3) * 16 + colw) * 8 + (k & 7);
            wlds[o] = h;
            wlds[KT16 + o] = f2bf(w - bf2f(h));
        }
        for (int k = kb; k < 1024; k += 32) {
            float w = WB[(size_t)k * 1024 + cstart + colw];
            unsigned short h = f2bf(w);
            int gk = KA + k;
            int o = ((gk >> 3) * 16 + colw) * 8 + (gk & 7);
            wlds[o] = h;
            wlds[KT16 + o] = f2bf(w - bf2f(h));
        }
    }
    // ---- one-time: zero H state (4 MB spread over 256 blocks) ----
    {
        int4 z = make_int4(0, 0, 0, 0);
        int4* hz = (int4*)((char*)Hws + (size_t)bid * 16384);
        hz[tid * 2] = z;
        hz[tid * 2 + 1] = z;
    }
    grid.sync();

    int lane = tid & 63, wid = tid >> 6;
    int lrow = lane & 15, kgrp = lane >> 4;
    int arow = wid * 16 + lrow;                       // batch row for A/D frags
    float bsum = bA[cstart + lrow] + bB[cstart + lrow];

    for (int p = 0; p <= S_LEN; ++p) {
        bool act = (layer == 0) ? (p < S_LEN) : (p > 0);
        if (act) {
            int rp = (p + 1) & 1, wp = p & 1;
            const unsigned short* h0p = Hws + (size_t)((dir * 2 + rp) * 2) * 131072;
            const unsigned short* h1p = Hws + (size_t)(((2 + dir) * 2 + rp) * 2) * 131072;

            f32x4 acc0 = {0.f, 0.f, 0.f, 0.f}, acc1 = {0.f, 0.f, 0.f, 0.f};

            if (layer == 0) {
                if (tid < 128) {
                    int t = dir ? (S_LEN - 1 - p) : p;
                    idxs[tid] = x[tid * S_LEN + t];
                }
                __syncthreads();
                const float* erow = emb + (size_t)idxs[arow] * 512;
                #pragma unroll 2
                for (int s = 0; s < 16; s += 2) {
                    bf16x8 ah, al;
                    int kk = s * 32 + kgrp * 8;
                    ld_e(erow, kk, ah, al);
                    acc0 = triple(wlds, KT16, (kk >> 3) * 16 + lrow, ah, al, acc0);
                    kk += 32;
                    ld_e(erow, kk, ah, al);
                    acc1 = triple(wlds, KT16, (kk >> 3) * 16 + lrow, ah, al, acc1);
                }
                const unsigned short* ar = h0p + (size_t)arow * 1024;
                #pragma unroll 2
                for (int s = 16; s < 48; s += 2) {
                    int kk = s * 32 + kgrp * 8;
                    bf16x8 ah = *(const bf16x8*)(ar + kk - 512);
                    bf16x8 al = *(const bf16x8*)(ar + 131072 + kk - 512);
                    acc0 = triple(wlds, KT16, (kk >> 3) * 16 + lrow, ah, al, acc0);
                    kk += 32;
                    ah = *(const bf16x8*)(ar + kk - 512);
                    al = *(const bf16x8*)(ar + 131072 + kk - 512);
                    acc1 = triple(wlds, KT16, (kk >> 3) * 16 + lrow, ah, al, acc1);
                }
            } else {
                const unsigned short* ar0 = h0p + (size_t)arow * 1024;
                #pragma unroll 2
                for (int s = 0; s < 32; s += 2) {
                    int kk = s * 32 + kgrp * 8;
                    bf16x8 ah = *(const bf16x8*)(ar0 + kk);
                    bf16x8 al = *(const bf16x8*)(ar0 + 131072 + kk);
                    acc0 = triple(wlds, KT16, (kk >> 3) * 16 + lrow, ah, al, acc0);
                    kk += 32;
                    ah = *(const bf16x8*)(ar0 + kk);
                    al = *(const bf16x8*)(ar0 + 131072 + kk);
                    acc1 = triple(wlds, KT16, (kk >> 3) * 16 + lrow, ah, al, acc1);
                }
                const unsigned short* ar1 = h1p + (size_t)arow * 1024;
                #pragma unroll 2
                for (int s = 32; s < 64; s += 2) {
                    int kk = s * 32 + kgrp * 8;
                    bf16x8 ah = *(const bf16x8*)(ar1 + kk - 1024);
                    bf16x8 al = *(const bf16x8*)(ar1 + 131072 + kk - 1024);
                    acc0 = triple(wlds, KT16, (kk >> 3) * 16 + lrow, ah, al, acc0);
                    kk += 32;
                    ah = *(const bf16x8*)(ar1 + kk - 1024);
                    al = *(const bf16x8*)(ar1 + 131072 + kk - 1024);
                    acc1 = triple(wlds, KT16, (kk >> 3) * 16 + lrow, ah, al, acc1);
                }
            }

            // bias + tanh + hi/lo split + store (D: col=lane&15, row=(lane>>4)*4+r)
            f32x4 acc = acc0 + acc1;
            unsigned short* wsl = Hws + (size_t)(((layer * 2 + dir) * 2 + wp) * 2) * 131072;
            bool fin = (layer == 1) && (p == S_LEN);
            #pragma unroll
            for (int r = 0; r < 4; ++r) {
                float v = tanhf(acc[r] + bsum);
                unsigned short h = f2bf(v);
                unsigned short l = f2bf(v - bf2f(h));
                int row = wid * 16 + kgrp * 4 + r;
                size_t o = (size_t)row * 1024 + cstart + lrow;
                wsl[o] = h;
                wsl[131072 + o] = l;
                if (fin) Hfin[(size_t)dir * 131072 + o] = v;
            }
        }
        grid.sync();
    }
}

// ---------------------------------------------------------------------------
// Epilogue: out = (concat(h_fwd, h_bwd) @ fc1 + b1) @ fc2 + b2
// ---------------------------------------------------------------------------
__global__ __launch_bounds__(64) void fc1_kernel(
    const float* __restrict__ fc1W, const float* __restrict__ fc1b,
    const float* __restrict__ Hfin, float* __restrict__ fc1out)
{
    int r = blockIdx.x;      // 0..127
    int c = threadIdx.x;     // 0..63
    const float* hf = Hfin + (size_t)r * 1024;
    const float* hb = Hfin + 131072 + (size_t)r * 1024;
    float s = fc1b[c];
    for (int k = 0; k < 1024; ++k) s += hf[k] * fc1W[k * 64 + c];
    for (int k = 0; k < 1024; ++k) s += hb[k] * fc1W[(1024 + k) * 64 + c];
    fc1out[r * 64 + c] = s;
}

__global__ __launch_bounds__(256) void fc2_kernel(
    const float* __restrict__ fc2W, const float* __restrict__ fc2b,
    const float* __restrict__ fc1out, float* __restrict__ out)
{
    int tid = threadIdx.x;   // 128 rows x 2 cols
    int r = tid >> 1, c = tid & 1;
    const float* f = fc1out + r * 64;
    float s = fc2b[c];
    for (int k = 0; k < 64; ++k) s += f[k] * fc2W[k * 2 + c];
    out[r * 2 + c] = s;
}

extern "C" void kernel_launch(void* const* d_in, const int* in_sizes, int n_in,
                              void* d_out, int out_size, void* d_ws, size_t ws_size,
                              hipStream_t stream)
{
    const int*   x    = (const int*)d_in[0];
    const float* emb  = (const float*)d_in[1];
    const float* f0Wi = (const float*)d_in[2];
    const float* f0bi = (const float*)d_in[3];
    const float* f0Wh = (const float*)d_in[4];
    const float* f0bh = (const float*)d_in[5];
    const float* f1Wi = (const float*)d_in[6];
    const float* f1bi = (const float*)d_in[7];
    const float* f1Wh = (const float*)d_in[8];
    const float* f1bh = (const float*)d_in[9];
    const float* b0Wi = (const float*)d_in[10];
    const float* b0bi = (const float*)d_in[11];
    const float* b0Wh = (const float*)d_in[12];
    const float* b0bh = (const float*)d_in[13];
    const float* b1Wi = (const float*)d_in[14];
    const float* b1bi = (const float*)d_in[15];
    const float* b1Wh = (const float*)d_in[16];
    const float* b1bh = (const float*)d_in[17];
    const float* fc1W = (const float*)d_in[18];
    const float* fc1b = (const float*)d_in[19];
    const float* fc2W = (const float*)d_in[20];
    const float* fc2b = (const float*)d_in[21];
    float* out = (float*)d_out;

    char* wsb = (char*)d_ws;
    unsigned short* Hws = (unsigned short*)wsb;
    float* Hfin   = (float*)(wsb + 4194304);
    float* fc1out = (float*)(wsb + 5242880);

    void* args[] = { (void*)&x, (void*)&emb,
                     (void*)&f0Wi, (void*)&f0Wh, (void*)&f1Wi, (void*)&f1Wh,
                     (void*)&b0Wi, (void*)&b0Wh, (void*)&b1Wi, (void*)&b1Wh,
                     (void*)&f0bi, (void*)&f0bh, (void*)&f1bi, (void*)&f1bh,
                     (void*)&b0bi, (void*)&b0bh, (void*)&b1bi, (void*)&b1bh,
                     (void*)&Hws, (void*)&Hfin };
    hipLaunchCooperativeKernel((void*)rnn_persistent, dim3(256), dim3(512),
                               args, 0, stream);

    fc1_kernel<<<128, 64, 0, stream>>>(fc1W, fc1b, Hfin, fc1out);
    fc2_kernel<<<1, 256, 0, stream>>>(fc2W, fc2b, fc1out, out);
}

// Round 4
// 28533.728 us; speedup vs baseline: 1.0783x; 1.0783x over previous
//
#include <hip/hip_runtime.h>

// BiRNN: B=128, S=512, E=512, H=1024, V=50000, C=2
// Skewed recurrence, one fused dispatch per phase:
// 224 K-split GEMM blocks (bf16x3 MFMA) + split-K "last block finishes tile"
// (atomic arrival counter -> finisher does reduce+bias+tanh+hi/lo store)
// + 8 rider blocks preparing next phase's embedding operand.

#define S_LEN 512

typedef short bf16x8 __attribute__((ext_vector_type(8)));
typedef float f32x4 __attribute__((ext_vector_type(4)));

__device__ __forceinline__ unsigned short f2bf(float f) {
    unsigned u = __float_as_uint(f);
    u += 0x7fff + ((u >> 16) & 1);
    return (unsigned short)(u >> 16);
}
__device__ __forceinline__ float bf2f(unsigned short h) {
    return __uint_as_float(((unsigned)h) << 16);
}
__device__ __forceinline__ f32x4 mfma16(bf16x8 a, bf16x8 b, f32x4 c) {
    return __builtin_amdgcn_mfma_f32_16x16x32_bf16(a, b, c, 0, 0, 0);
}

// ws layout (bytes):
//  WThi @ 0          (14,680,064)  [2 dir][3,670,016] ushort, transposed frag-order
//  WTlo @ 14,680,064 (14,680,064)
//  Hhi  @ 29,360,128 ( 2,097,152)  [2 hsel][2 dir][2 par] x 131072 ushort
//  Hlo  @ 31,457,280 ( 2,097,152)
//  Ehi  @ 33,554,432 (   524,288)  [2 dir][2 par] x 65536 ushort
//  Elo  @ 34,078,720 (   524,288)
//  PART @ 34,603,008 (16,777,216)  [2][16 stripe][8 chunk][16384] f32
//  CNT  @ 34,996,224 (       128)  32 ints (PART dir0/stripe0/chunk6 slack --
//                                  h0 tiles never write chunks 6,7)
//  FC1  @ 51,380,224 (    32,768)

// ---------------------------------------------------------------------------
// One-time weight conversion: W[K][1024] fp32 -> WT_hi/lo [1024][K] bf16
// ---------------------------------------------------------------------------
__global__ __launch_bounds__(256) void conv_weight(
    const float* __restrict__ W, unsigned short* __restrict__ dhi,
    unsigned short* __restrict__ dlo, int K)
{
    int t = blockIdx.x * 256 + threadIdx.x;
    int n = t & 1023;
    int k0 = (t >> 10) << 3;
    if (k0 >= K) return;
    unsigned short hh[8], ll[8];
    #pragma unroll
    for (int j = 0; j < 8; ++j) {
        float w = W[(size_t)(k0 + j) * 1024 + n];
        unsigned short h = f2bf(w);
        hh[j] = h;
        ll[j] = f2bf(w - bf2f(h));
    }
    size_t o = (size_t)n * K + k0;
    *(ushort4*)(dhi + o)     = make_ushort4(hh[0], hh[1], hh[2], hh[3]);
    *(ushort4*)(dhi + o + 4) = make_ushort4(hh[4], hh[5], hh[6], hh[7]);
    *(ushort4*)(dlo + o)     = make_ushort4(ll[0], ll[1], ll[2], ll[3]);
    *(ushort4*)(dlo + o + 4) = make_ushort4(ll[4], ll[5], ll[6], ll[7]);
}

// ---------------------------------------------------------------------------
// Embedding gather + hi/lo split for phase pc (double-buffered by pc&1)
// eb in 0..7: dir = eb>>2, rowgroup = eb&3 (32 rows each). 512 threads.
// ---------------------------------------------------------------------------
__device__ __forceinline__ void prep_e(int eb, int tid, const int* __restrict__ x,
    const float* __restrict__ emb, unsigned short* __restrict__ Ehi,
    unsigned short* __restrict__ Elo, int pc)
{
    if (pc > 511) return;
    int dir = eb >> 2, rg = eb & 3;
    int tsel = dir ? (511 - pc) : pc;
    int pe = pc & 1;
    unsigned short* ehi = Ehi + (size_t)(dir * 2 + pe) * 65536;
    unsigned short* elo = Elo + (size_t)(dir * 2 + pe) * 65536;
    for (int i = 0; i < 8; ++i) {
        int q = i * 512 + tid;          // 0..4095
        int rowl = q >> 7;              // 0..31
        int c4 = (q & 127) * 4;
        int m = rg * 32 + rowl;
        int idx = x[m * S_LEN + tsel];
        float4 v = *(const float4*)(emb + (size_t)idx * 512 + c4);
        ushort4 h4, l4;
        h4.x = f2bf(v.x); l4.x = f2bf(v.x - bf2f(h4.x));
        h4.y = f2bf(v.y); l4.y = f2bf(v.y - bf2f(h4.y));
        h4.z = f2bf(v.z); l4.z = f2bf(v.z - bf2f(h4.z));
        h4.w = f2bf(v.w); l4.w = f2bf(v.w - bf2f(h4.w));
        *(ushort4*)(ehi + (size_t)m * 512 + c4) = h4;
        *(ushort4*)(elo + (size_t)m * 512 + c4) = l4;
    }
}

__global__ __launch_bounds__(512) void prep_e_kernel(const int* __restrict__ x,
    const float* __restrict__ emb, unsigned short* __restrict__ Ehi,
    unsigned short* __restrict__ Elo, int pc)
{
    prep_e(blockIdx.x, threadIdx.x, x, emb, Ehi, Elo, pc);
}

// ---------------------------------------------------------------------------
// Fused phase kernel: GEMM chunks + last-arriver reduce+tanh. 232 blocks x 512.
// ---------------------------------------------------------------------------
__global__ __launch_bounds__(512) void rnn_phase(
    const unsigned short* __restrict__ WThi, const unsigned short* __restrict__ WTlo,
    unsigned short* __restrict__ Hhi, unsigned short* __restrict__ Hlo,
    unsigned short* __restrict__ Ehi, unsigned short* __restrict__ Elo,
    const int* __restrict__ x, const float* __restrict__ emb,
    const float* __restrict__ f0bi, const float* __restrict__ f0bh,
    const float* __restrict__ f1bi, const float* __restrict__ f1bh,
    const float* __restrict__ b0bi, const float* __restrict__ b0bh,
    const float* __restrict__ b1bi, const float* __restrict__ b1bh,
    float* __restrict__ part, int* __restrict__ cnt, int p)
{
    __shared__ int fin;
    int bid = blockIdx.x, tid = threadIdx.x;
    if (bid >= 224) { prep_e(bid - 224, tid, x, emb, Ehi, Elo, p + 1); return; }

    int dir = bid / 112;
    int r = bid % 112;
    int stripe, chunk;
    if (r < 48) { stripe = r / 6; chunk = r % 6; }
    else        { int r2 = r - 48; stripe = 8 + (r2 >> 3); chunk = r2 & 7; }
    bool isH0 = stripe < 8;
    if (isH0 && p == S_LEN) return;
    if (!isH0 && p == 0)    return;
    int rp = (p + 1) & 1;
    int nparts = isH0 ? 6 : 8;

    int matoff, Kmat, koff, hsel = 0;
    bool egather = false;
    if (isH0) {
        if (chunk < 2) { egather = true; matoff = 0; Kmat = 512; koff = chunk * 256; }
        else           { matoff = 524288;  Kmat = 1024; koff = chunk * 256 - 512;  hsel = 0; }
    } else {
        if (chunk < 4) { matoff = 1572864; Kmat = 1024; koff = chunk * 256;        hsel = 0; }
        else           { matoff = 2621440; Kmat = 1024; koff = chunk * 256 - 1024; hsel = 1; }
    }
    const unsigned short* wbhi = WThi + (size_t)dir * 3670016 + matoff;
    const unsigned short* wblo = WTlo + (size_t)dir * 3670016 + matoff;
    const unsigned short* abhi;
    const unsigned short* ablo;
    int astride;
    if (egather) {
        abhi = Ehi + (size_t)(dir * 2 + (p & 1)) * 65536;
        ablo = Elo + (size_t)(dir * 2 + (p & 1)) * 65536;
        astride = 512;
    } else {
        abhi = Hhi + (size_t)((hsel * 2 + dir) * 2 + rp) * 131072;
        ablo = Hlo + (size_t)((hsel * 2 + dir) * 2 + rp) * 131072;
        astride = 1024;
    }

    int lane = tid & 63, wid = tid >> 6;
    int wm = (wid >> 2) * 64;       // wave row base (0/64)
    int wn = (wid & 3) * 32;        // wave col base (0/32/64/96)
    int lrow = lane & 15;
    int kgrp = lane >> 4;
    int cstart = (stripe & 7) * 128;

    int arow[4], ncol[2];
    #pragma unroll
    for (int i = 0; i < 4; ++i) arow[i] = wm + i * 16 + lrow;
    #pragma unroll
    for (int j = 0; j < 2; ++j) ncol[j] = cstart + wn + j * 16 + lrow;

    f32x4 acc[4][2];
    #pragma unroll
    for (int i = 0; i < 4; ++i)
        #pragma unroll
        for (int j = 0; j < 2; ++j) acc[i][j] = (f32x4){0.f, 0.f, 0.f, 0.f};

    #pragma unroll 2
    for (int s = 0; s < 8; ++s) {
        int kk = koff + s * 32 + kgrp * 8;
        bf16x8 ahi[4], alo[4], bhi[2], blo[2];
        #pragma unroll
        for (int i = 0; i < 4; ++i) {
            size_t ao = (size_t)arow[i] * astride + kk;
            ahi[i] = *(const bf16x8*)(abhi + ao);
            alo[i] = *(const bf16x8*)(ablo + ao);
        }
        #pragma unroll
        for (int j = 0; j < 2; ++j) {
            size_t bo = (size_t)ncol[j] * Kmat + kk;
            bhi[j] = *(const bf16x8*)(wbhi + bo);
            blo[j] = *(const bf16x8*)(wblo + bo);
        }
        #pragma unroll
        for (int i = 0; i < 4; ++i)
            #pragma unroll
            for (int j = 0; j < 2; ++j) {
                acc[i][j] = mfma16(ahi[i], bhi[j], acc[i][j]);
                acc[i][j] = mfma16(ahi[i], blo[j], acc[i][j]);
                acc[i][j] = mfma16(alo[i], bhi[j], acc[i][j]);
            }
    }

    int tile = dir * 16 + stripe;
    float* outp = part + (size_t)(tile * 8 + chunk) * 16384;
    #pragma unroll
    for (int i = 0; i < 4; ++i)
        #pragma unroll
        for (int j = 0; j < 2; ++j) {
            int col = wn + j * 16 + lrow;
            #pragma unroll
            for (int r4 = 0; r4 < 4; ++r4) {
                int row = wm + i * 16 + kgrp * 4 + r4;
                outp[row * 128 + col] = acc[i][j][r4];
            }
        }

    // ---- arrival: last block of this tile does the reduce+tanh ----
    __syncthreads();   // each wave drains vmcnt before barrier -> stores issued
    if (tid == 0) {
        int old = __hip_atomic_fetch_add(&cnt[tile], 1,
                                         __ATOMIC_ACQ_REL, __HIP_MEMORY_SCOPE_AGENT);
        fin = (old == nparts - 1) ? 1 : 0;
    }
    __syncthreads();
    if (!fin) return;

    // finisher: sum nparts chunks, bias + tanh, hi/lo split, store h
    const float* pb = part + (size_t)(tile * 8) * 16384;
    int wpar = p & 1;
    int hout = isH0 ? 0 : 1;
    unsigned short* dh = Hhi + (size_t)((hout * 2 + dir) * 2 + wpar) * 131072;
    unsigned short* dl = Hlo + (size_t)((hout * 2 + dir) * 2 + wpar) * 131072;
    const float *bA, *bB;
    if (isH0) { bA = dir ? b0bi : f0bi; bB = dir ? b0bh : f0bh; }
    else      { bA = dir ? b1bi : f1bi; bB = dir ? b1bh : f1bh; }

    for (int i = 0; i < 8; ++i) {
        int q = i * 512 + tid;          // 0..4095 float4-quads
        int row = q >> 5, c4 = (q & 31) * 4;
        int off = row * 128 + c4;
        float4 s = *(const float4*)(pb + off);
        for (int u = 1; u < nparts; ++u) {
            float4 v = *(const float4*)(pb + (size_t)u * 16384 + off);
            s.x += v.x; s.y += v.y; s.z += v.z; s.w += v.w;
        }
        int gc = cstart + c4;
        s.x = tanhf(s.x + bA[gc]     + bB[gc]);
        s.y = tanhf(s.y + bA[gc + 1] + bB[gc + 1]);
        s.z = tanhf(s.z + bA[gc + 2] + bB[gc + 2]);
        s.w = tanhf(s.w + bA[gc + 3] + bB[gc + 3]);
        ushort4 h4, l4;
        h4.x = f2bf(s.x); l4.x = f2bf(s.x - bf2f(h4.x));
        h4.y = f2bf(s.y); l4.y = f2bf(s.y - bf2f(h4.y));
        h4.z = f2bf(s.z); l4.z = f2bf(s.z - bf2f(h4.z));
        h4.w = f2bf(s.w); l4.w = f2bf(s.w - bf2f(h4.w));
        *(ushort4*)(dh + (size_t)row * 1024 + gc) = h4;
        *(ushort4*)(dl + (size_t)row * 1024 + gc) = l4;
    }
    if (tid == 0)
        __hip_atomic_store(&cnt[tile], 0, __ATOMIC_RELAXED, __HIP_MEMORY_SCOPE_AGENT);
}

// ---------------------------------------------------------------------------
// Epilogue: out = (concat(h_fwd, h_bwd) @ fc1 + b1) @ fc2 + b2
// ---------------------------------------------------------------------------
__global__ __launch_bounds__(64) void fc1_kernel(
    const float* __restrict__ fc1W, const float* __restrict__ fc1b,
    const unsigned short* __restrict__ Hhi, const unsigned short* __restrict__ Hlo,
    float* __restrict__ fc1out)
{
    int r = blockIdx.x;      // 0..127
    int c = threadIdx.x;     // 0..63
    const unsigned short* fh = Hhi + (size_t)4 * 131072 + r * 1024; // layer1 dir0 par0
    const unsigned short* fl = Hlo + (size_t)4 * 131072 + r * 1024;
    const unsigned short* bh = Hhi + (size_t)6 * 131072 + r * 1024; // layer1 dir1 par0
    const unsigned short* bl = Hlo + (size_t)6 * 131072 + r * 1024;
    float s = fc1b[c];
    for (int k = 0; k < 1024; ++k)
        s += (bf2f(fh[k]) + bf2f(fl[k])) * fc1W[k * 64 + c];
    for (int k = 0; k < 1024; ++k)
        s += (bf2f(bh[k]) + bf2f(bl[k])) * fc1W[(1024 + k) * 64 + c];
    fc1out[r * 64 + c] = s;
}

__global__ __launch_bounds__(256) void fc2_kernel(
    const float* __restrict__ fc2W, const float* __restrict__ fc2b,
    const float* __restrict__ fc1out, float* __restrict__ out)
{
    int tid = threadIdx.x;   // 128 rows x 2 cols
    int r = tid >> 1, c = tid & 1;
    const float* f = fc1out + r * 64;
    float s = fc2b[c];
    for (int k = 0; k < 64; ++k) s += f[k] * fc2W[k * 2 + c];
    out[r * 2 + c] = s;
}

extern "C" void kernel_launch(void* const* d_in, const int* in_sizes, int n_in,
                              void* d_out, int out_size, void* d_ws, size_t ws_size,
                              hipStream_t stream)
{
    const int*   x    = (const int*)d_in[0];
    const float* emb  = (const float*)d_in[1];
    const float* f0Wi = (const float*)d_in[2];
    const float* f0bi = (const float*)d_in[3];
    const float* f0Wh = (const float*)d_in[4];
    const float* f0bh = (const float*)d_in[5];
    const float* f1Wi = (const float*)d_in[6];
    const float* f1bi = (const float*)d_in[7];
    const float* f1Wh = (const float*)d_in[8];
    const float* f1bh = (const float*)d_in[9];
    const float* b0Wi = (const float*)d_in[10];
    const float* b0bi = (const float*)d_in[11];
    const float* b0Wh = (const float*)d_in[12];
    const float* b0bh = (const float*)d_in[13];
    const float* b1Wi = (const float*)d_in[14];
    const float* b1bi = (const float*)d_in[15];
    const float* b1Wh = (const float*)d_in[16];
    const float* b1bh = (const float*)d_in[17];
    const float* fc1W = (const float*)d_in[18];
    const float* fc1b = (const float*)d_in[19];
    const float* fc2W = (const float*)d_in[20];
    const float* fc2b = (const float*)d_in[21];
    float* out = (float*)d_out;

    char* wsb = (char*)d_ws;
    unsigned short* WThi = (unsigned short*)(wsb);
    unsigned short* WTlo = (unsigned short*)(wsb + 14680064);
    unsigned short* Hhi  = (unsigned short*)(wsb + 29360128);
    unsigned short* Hlo  = (unsigned short*)(wsb + 31457280);
    unsigned short* Ehi  = (unsigned short*)(wsb + 33554432);
    unsigned short* Elo  = (unsigned short*)(wsb + 34078720);
    float* part   = (float*)(wsb + 34603008);
    int*   cnt    = (int*)(wsb + 34996224);
    float* fc1out = (float*)(wsb + 51380224);

    // one-time weight conversion (8 matrices)
    conv_weight<<<256, 256, 0, stream>>>(f0Wi, WThi + 0,       WTlo + 0,       512);
    conv_weight<<<512, 256, 0, stream>>>(f0Wh, WThi + 524288,  WTlo + 524288,  1024);
    conv_weight<<<512, 256, 0, stream>>>(f1Wi, WThi + 1572864, WTlo + 1572864, 1024);
    conv_weight<<<512, 256, 0, stream>>>(f1Wh, WThi + 2621440, WTlo + 2621440, 1024);
    conv_weight<<<256, 256, 0, stream>>>(b0Wi, WThi + 3670016,           WTlo + 3670016,           512);
    conv_weight<<<512, 256, 0, stream>>>(b0Wh, WThi + 3670016 + 524288,  WTlo + 3670016 + 524288,  1024);
    conv_weight<<<512, 256, 0, stream>>>(b1Wi, WThi + 3670016 + 1572864, WTlo + 3670016 + 1572864, 1024);
    conv_weight<<<512, 256, 0, stream>>>(b1Wh, WThi + 3670016 + 2621440, WTlo + 3670016 + 2621440, 1024);

    // zero h state (hi+lo, all layers/dirs/parities) and arrival counters
    hipMemsetAsync(wsb + 29360128, 0, 4194304, stream);
    hipMemsetAsync(wsb + 34996224, 0, 128, stream);
    // initial embedding operand for phase 0
    prep_e_kernel<<<8, 512, 0, stream>>>(x, emb, Ehi, Elo, 0);

    for (int p = 0; p <= S_LEN; ++p) {
        rnn_phase<<<232, 512, 0, stream>>>(WThi, WTlo, Hhi, Hlo, Ehi, Elo,
                                           x, emb,
                                           f0bi, f0bh, f1bi, f1bh,
                                           b0bi, b0bh, b1bi, b1bh,
                                           part, cnt, p);
    }
    fc1_kernel<<<128, 64, 0, stream>>>(fc1W, fc1b, Hhi, Hlo, fc1out);
    fc2_kernel<<<1, 256, 0, stream>>>(fc2W, fc2b, fc1out, out);
}

// Round 5
// 16199.420 us; speedup vs baseline: 1.8994x; 1.7614x over previous
//
#include <hip/hip_runtime.h>

// BiRNN: B=128, S=512, E=512, H=1024, V=50000, C=2
// Persistent cooperative kernel, 224 blocks (1/CU), round-2 split-K layout:
//   h0 tiles: 8 stripes x 6 K-chunks (2 egather + 4 recurrent), per dir
//   h1 tiles: 8 stripes x 8 K-chunks, per dir
// Weights LDS-resident (bf16 hi/lo, frag order). A staged through 16KB LDS.
// ALL cross-phase state via relaxed agent-scope atomics (sc1 -> LLC), no
// cache-maintenance fences. Hand-rolled monotonic-counter barrier, 2/phase.

#define S_LEN 512

typedef short bf16x8 __attribute__((ext_vector_type(8)));
typedef float f32x4 __attribute__((ext_vector_type(4)));

__device__ __forceinline__ unsigned short f2bf(float f) {
    unsigned u = __float_as_uint(f);
    u += 0x7fff + ((u >> 16) & 1);
    return (unsigned short)(u >> 16);
}
__device__ __forceinline__ float bf2f(unsigned short h) {
    return __uint_as_float(((unsigned)h) << 16);
}
__device__ __forceinline__ f32x4 mfma16(bf16x8 a, bf16x8 b, f32x4 c) {
    return __builtin_amdgcn_mfma_f32_16x16x32_bf16(a, b, c, 0, 0, 0);
}
// relaxed agent-scope (sc1, coherence-point) accesses
__device__ __forceinline__ unsigned long long ld8_cc(const void* p) {
    return __hip_atomic_load((unsigned long long*)p, __ATOMIC_RELAXED,
                             __HIP_MEMORY_SCOPE_AGENT);
}
__device__ __forceinline__ void st8_cc(void* p, unsigned long long v) {
    __hip_atomic_store((unsigned long long*)p, v, __ATOMIC_RELAXED,
                       __HIP_MEMORY_SCOPE_AGENT);
}
__device__ __forceinline__ void st4_cc(void* p, float v) {
    __hip_atomic_store((int*)p, __float_as_int(v), __ATOMIC_RELAXED,
                       __HIP_MEMORY_SCOPE_AGENT);
}

union U8  { unsigned long long u; float f[2]; unsigned short s[4]; };
union F16 { bf16x8 v; unsigned long long u[2]; unsigned short s[8]; };

// ws layout (bytes):
//  part @ 0          : [32 tile][8 chunk][128][128] f32 = 16,777,216
//  Hhi  @ 16,777,216 : 8 slices x 131072 ushort = 2,097,152
//  Hlo  @ 18,874,368 : 2,097,152
//  Hfin @ 20,971,520 : [2 dir][128][1024] f32 = 1,048,576
//  cnt  @ 22,020,096 : 8 counters x 64B = 512
//  fc1  @ 22,020,608 : 32,768

// monotonic-counter barrier: 224 arrivals/epoch spread over 8 padded counters
__device__ __forceinline__ void gbar(int* cnt, int bid, int tid, int target) {
    __syncthreads();   // drains each wave's vmcnt -> all sc1 stores LLC-acked
    if (tid == 0) {
        __hip_atomic_fetch_add(cnt + (bid & 7) * 16, 1, __ATOMIC_RELAXED,
                               __HIP_MEMORY_SCOPE_AGENT);
        int s;
        do {
            s = 0;
            #pragma unroll
            for (int j = 0; j < 8; ++j)
                s += __hip_atomic_load(cnt + j * 16, __ATOMIC_RELAXED,
                                       __HIP_MEMORY_SCOPE_AGENT);
            if (s < target) __builtin_amdgcn_s_sleep(1);
        } while (s < target);
    }
    __syncthreads();
}

__global__ __launch_bounds__(512) void rnn_persist(
    const int* __restrict__ x, const float* __restrict__ emb,
    const float* __restrict__ f0Wi, const float* __restrict__ f0Wh,
    const float* __restrict__ f1Wi, const float* __restrict__ f1Wh,
    const float* __restrict__ b0Wi, const float* __restrict__ b0Wh,
    const float* __restrict__ b1Wi, const float* __restrict__ b1Wh,
    const float* __restrict__ f0bi, const float* __restrict__ f0bh,
    const float* __restrict__ f1bi, const float* __restrict__ f1bh,
    const float* __restrict__ b0bi, const float* __restrict__ b0bh,
    const float* __restrict__ b1bi, const float* __restrict__ b1bh,
    unsigned short* __restrict__ Hhi, unsigned short* __restrict__ Hlo,
    float* __restrict__ part, int* __restrict__ cnt, float* __restrict__ Hfin)
{
    // LDS: [0,32768) W-hi  [32768,65536) W-lo  (frag order, tile k x 128 cols)
    //      [65536,69632) A-stage hi  [69632,73728) A-stage lo   (128 rows x 32 k)
    __shared__ unsigned short lds[73728];   // 144 KiB

    const int bid = blockIdx.x, tid = threadIdx.x;
    const int dir = bid / 112;
    const int rr = bid % 112;
    int stripe, chunk;
    if (rr < 48) { stripe = rr / 6; chunk = rr % 6; }
    else         { int r2 = rr - 48; stripe = 8 + (r2 >> 3); chunk = r2 & 7; }
    const bool isH0 = stripe < 8;
    const bool eg = isH0 && (chunk < 2);
    const int nparts = isH0 ? 6 : 8;
    const int cstart = (stripe & 7) * 128;
    const int tile = dir * 16 + stripe;
    const int hout = isH0 ? 0 : 1;

    // weight source + k-offset within that matrix
    const float* Wsrc; int koffw; int hselA = 0;
    if (isH0) {
        if (eg) { Wsrc = dir ? b0Wi : f0Wi; koffw = chunk * 256; }
        else    { Wsrc = dir ? b0Wh : f0Wh; koffw = chunk * 256 - 512; }
    } else {
        if (chunk < 4) { Wsrc = dir ? b1Wi : f1Wi; koffw = chunk * 256;        hselA = 0; }
        else           { Wsrc = dir ? b1Wh : f1Wh; koffw = chunk * 256 - 1024; hselA = 1; }
    }
    const float *bA, *bB;
    if (isH0) { bA = dir ? b0bi : f0bi; bB = dir ? b0bh : f0bh; }
    else      { bA = dir ? b1bi : f1bi; bB = dir ? b1bh : f1bh; }

    // ---- one-time: weight tile -> LDS (hi/lo, frag order) ----
    for (int q = tid; q < 32768; q += 512) {
        int k = q >> 7, c = q & 127;
        float w = Wsrc[(size_t)(koffw + k) * 1024 + cstart + c];
        unsigned short h = f2bf(w);
        int o = ((k >> 3) * 128 + c) * 8 + (k & 7);
        lds[o] = h;
        lds[32768 + o] = f2bf(w - bf2f(h));
    }

    const int lane = tid & 63, wid = tid >> 6;
    const int wm = (wid >> 2) * 64, wn = (wid & 3) * 32;
    const int lrow = lane & 15, kgrp = lane >> 4;
    const int srow = tid >> 2;          // stager row 0..127
    const int skq  = tid & 3;           // stager k-quarter
    const int sk   = skq * 8;           // k-elem offset within 32-k step

    float* myPart = part + (size_t)(tile * 8 + chunk) * 16384;
    const float* pb = part + (size_t)tile * 8 * 16384;
    const int r0 = (chunk * 128) / nparts, r1 = ((chunk + 1) * 128) / nparts;

#define ISSUE(E0, E1, GH, GL, sv)                                              \
    do { if (eg) {                                                             \
            const float* ep_ = erow + (sv) * 32;                               \
            E0 = *(const float4*)(ep_); E1 = *(const float4*)(ep_ + 4);        \
        } else {                                                               \
            GH.u[0] = ld8_cc(ahB + (sv) * 32); GH.u[1] = ld8_cc(ahB + (sv) * 32 + 4); \
            GL.u[0] = ld8_cc(alB + (sv) * 32); GL.u[1] = ld8_cc(alB + (sv) * 32 + 4); \
        } } while (0)

#define STAGE(E0, E1, GH, GL)                                                  \
    do { int ao_ = (skq * 128 + srow) * 8;                                     \
        if (eg) {                                                              \
            F16 hh_, ll_;                                                      \
            float ev_[8] = {E0.x, E0.y, E0.z, E0.w, E1.x, E1.y, E1.z, E1.w};   \
            _Pragma("unroll") for (int j_ = 0; j_ < 8; ++j_) {                 \
                unsigned short h_ = f2bf(ev_[j_]);                             \
                hh_.s[j_] = h_; ll_.s[j_] = f2bf(ev_[j_] - bf2f(h_)); }        \
            *(bf16x8*)&lds[65536 + ao_] = hh_.v;                               \
            *(bf16x8*)&lds[69632 + ao_] = ll_.v;                               \
        } else {                                                               \
            *(bf16x8*)&lds[65536 + ao_] = GH.v;                                \
            *(bf16x8*)&lds[69632 + ao_] = GL.v; } } while (0)

#define CONSUME(sv)                                                            \
    do { bf16x8 bh_[2], bl_[2];                                                \
        _Pragma("unroll") for (int jj_ = 0; jj_ < 2; ++jj_) {                  \
            int bo_ = (((sv) * 4 + kgrp) * 128 + wn + jj_ * 16 + lrow) * 8;    \
            bh_[jj_] = *(const bf16x8*)&lds[bo_];                              \
            bl_[jj_] = *(const bf16x8*)&lds[32768 + bo_]; }                    \
        _Pragma("unroll") for (int i_ = 0; i_ < 4; ++i_) {                     \
            int ao_ = (kgrp * 128 + wm + i_ * 16 + lrow) * 8;                  \
            bf16x8 ah_ = *(const bf16x8*)&lds[65536 + ao_];                    \
            bf16x8 al_ = *(const bf16x8*)&lds[69632 + ao_];                    \
            _Pragma("unroll") for (int jj_ = 0; jj_ < 2; ++jj_) {              \
                acc[i_][jj_] = mfma16(ah_, bh_[jj_], acc[i_][jj_]);            \
                acc[i_][jj_] = mfma16(ah_, bl_[jj_], acc[i_][jj_]);            \
                acc[i_][jj_] = mfma16(al_, bh_[jj_], acc[i_][jj_]); } } } while (0)

    int ep = 0;
    for (int p = 0; p <= S_LEN; ++p) {
        const bool act = isH0 ? (p < S_LEN) : (p > 0);
        const int rp = (p + 1) & 1, wp = p & 1;

        if (act) {
            // ---- GEMM: 128x128 tile over this block's 256-k chunk ----
            const unsigned short* ahB = Hhi;
            const unsigned short* alB = Hlo;
            const float* erow = emb;
            if (eg) {
                int tsel = dir ? (S_LEN - 1 - p) : p;
                int idx = x[srow * S_LEN + tsel];
                erow = emb + (size_t)idx * 512 + koffw + sk;
            } else {
                size_t hb = (size_t)((hselA * 2 + dir) * 2 + rp) * 131072
                          + (size_t)srow * 1024 + koffw + sk;
                ahB = Hhi + hb;
                alB = Hlo + hb;
            }

            f32x4 acc[4][2];
            #pragma unroll
            for (int i = 0; i < 4; ++i)
                #pragma unroll
                for (int j = 0; j < 2; ++j) acc[i][j] = (f32x4){0.f, 0.f, 0.f, 0.f};

            float4 e0a, e1a, e0b, e1b;
            F16 ha, la, hb2, lb2;
            ISSUE(e0a, e1a, ha, la, 0);
            #pragma unroll
            for (int s = 0; s < 8; s += 2) {
                __syncthreads();                       // stage buffer free
                ISSUE(e0b, e1b, hb2, lb2, s + 1);
                STAGE(e0a, e1a, ha, la);
                __syncthreads();
                CONSUME(s);
                __syncthreads();
                if (s < 6) ISSUE(e0a, e1a, ha, la, s + 2);
                STAGE(e0b, e1b, hb2, lb2);
                __syncthreads();
                CONSUME(s + 1);
            }

            // partial store (sc1, 4B)
            #pragma unroll
            for (int i = 0; i < 4; ++i)
                #pragma unroll
                for (int jj = 0; jj < 2; ++jj) {
                    int col = wn + jj * 16 + lrow;
                    #pragma unroll
                    for (int r4 = 0; r4 < 4; ++r4) {
                        int row = wm + i * 16 + kgrp * 4 + r4;
                        st4_cc(myPart + row * 128 + col, acc[i][jj][r4]);
                    }
                }
        }

        ++ep; gbar(cnt, bid, tid, ep * 224);

        if (act) {
            // ---- reduce own row-slice of own tile + bias + tanh + h store ----
            unsigned short* dh = Hhi + (size_t)((hout * 2 + dir) * 2 + wp) * 131072;
            unsigned short* dl = Hlo + (size_t)((hout * 2 + dir) * 2 + wp) * 131072;
            const bool fin = (!isH0) && (p == S_LEN);
            const int nrows = r1 - r0;
            for (int u = tid; u < nrows * 32; u += 512) {
                int row = r0 + (u >> 5), cq = (u & 31) * 4;
                int off = row * 128 + cq;
                U8 a0, a1;
                a0.u = ld8_cc(pb + off); a1.u = ld8_cc(pb + off + 2);
                float s0 = a0.f[0], s1 = a0.f[1], s2 = a1.f[0], s3 = a1.f[1];
                for (int q = 1; q < nparts; ++q) {
                    const float* pq = pb + (size_t)q * 16384 + off;
                    a0.u = ld8_cc(pq); a1.u = ld8_cc(pq + 2);
                    s0 += a0.f[0]; s1 += a0.f[1]; s2 += a1.f[0]; s3 += a1.f[1];
                }
                int gc = cstart + cq;
                s0 = tanhf(s0 + bA[gc]     + bB[gc]);
                s1 = tanhf(s1 + bA[gc + 1] + bB[gc + 1]);
                s2 = tanhf(s2 + bA[gc + 2] + bB[gc + 2]);
                s3 = tanhf(s3 + bA[gc + 3] + bB[gc + 3]);
                U8 hu, lu;
                unsigned short h0 = f2bf(s0), h1 = f2bf(s1), h2 = f2bf(s2), h3 = f2bf(s3);
                hu.s[0] = h0; hu.s[1] = h1; hu.s[2] = h2; hu.s[3] = h3;
                lu.s[0] = f2bf(s0 - bf2f(h0)); lu.s[1] = f2bf(s1 - bf2f(h1));
                lu.s[2] = f2bf(s2 - bf2f(h2)); lu.s[3] = f2bf(s3 - bf2f(h3));
                size_t ho = (size_t)row * 1024 + gc;
                st8_cc(dh + ho, hu.u);
                st8_cc(dl + ho, lu.u);
                if (fin) {
                    float* fo = Hfin + (size_t)dir * 131072 + row * 1024 + gc;
                    st4_cc(fo, s0); st4_cc(fo + 1, s1);
                    st4_cc(fo + 2, s2); st4_cc(fo + 3, s3);
                }
            }
        }

        ++ep; gbar(cnt, bid, tid, ep * 224);
    }
#undef ISSUE
#undef STAGE
#undef CONSUME
}

// ---------------------------------------------------------------------------
// Epilogue: out = (concat(h_fwd, h_bwd) @ fc1 + b1) @ fc2 + b2
// ---------------------------------------------------------------------------
__global__ __launch_bounds__(64) void fc1_kernel(
    const float* __restrict__ fc1W, const float* __restrict__ fc1b,
    const float* __restrict__ Hfin, float* __restrict__ fc1out)
{
    int r = blockIdx.x;      // 0..127
    int c = threadIdx.x;     // 0..63
    const float* hf = Hfin + (size_t)r * 1024;
    const float* hb = Hfin + 131072 + (size_t)r * 1024;
    float s = fc1b[c];
    for (int k = 0; k < 1024; ++k) s += hf[k] * fc1W[k * 64 + c];
    for (int k = 0; k < 1024; ++k) s += hb[k] * fc1W[(1024 + k) * 64 + c];
    fc1out[r * 64 + c] = s;
}

__global__ __launch_bounds__(256) void fc2_kernel(
    const float* __restrict__ fc2W, const float* __restrict__ fc2b,
    const float* __restrict__ fc1out, float* __restrict__ out)
{
    int tid = threadIdx.x;   // 128 rows x 2 cols
    int r = tid >> 1, c = tid & 1;
    const float* f = fc1out + r * 64;
    float s = fc2b[c];
    for (int k = 0; k < 64; ++k) s += f[k] * fc2W[k * 2 + c];
    out[r * 2 + c] = s;
}

extern "C" void kernel_launch(void* const* d_in, const int* in_sizes, int n_in,
                              void* d_out, int out_size, void* d_ws, size_t ws_size,
                              hipStream_t stream)
{
    const int*   x    = (const int*)d_in[0];
    const float* emb  = (const float*)d_in[1];
    const float* f0Wi = (const float*)d_in[2];
    const float* f0bi = (const float*)d_in[3];
    const float* f0Wh = (const float*)d_in[4];
    const float* f0bh = (const float*)d_in[5];
    const float* f1Wi = (const float*)d_in[6];
    const float* f1bi = (const float*)d_in[7];
    const float* f1Wh = (const float*)d_in[8];
    const float* f1bh = (const float*)d_in[9];
    const float* b0Wi = (const float*)d_in[10];
    const float* b0bi = (const float*)d_in[11];
    const float* b0Wh = (const float*)d_in[12];
    const float* b0bh = (const float*)d_in[13];
    const float* b1Wi = (const float*)d_in[14];
    const float* b1bi = (const float*)d_in[15];
    const float* b1Wh = (const float*)d_in[16];
    const float* b1bh = (const float*)d_in[17];
    const float* fc1W = (const float*)d_in[18];
    const float* fc1b = (const float*)d_in[19];
    const float* fc2W = (const float*)d_in[20];
    const float* fc2b = (const float*)d_in[21];
    float* out = (float*)d_out;

    char* wsb = (char*)d_ws;
    float*          part = (float*)(wsb);
    unsigned short* Hhi  = (unsigned short*)(wsb + 16777216);
    unsigned short* Hlo  = (unsigned short*)(wsb + 18874368);
    float*          Hfin = (float*)(wsb + 20971520);
    int*            cnt  = (int*)(wsb + 22020096);
    float*          fc1out = (float*)(wsb + 22020608);

    // zero h state (both parities, hi+lo) and barrier counters, each launch
    hipMemsetAsync(wsb + 16777216, 0, 4194304, stream);
    hipMemsetAsync(wsb + 22020096, 0, 512, stream);

    void* args[] = { (void*)&x, (void*)&emb,
                     (void*)&f0Wi, (void*)&f0Wh, (void*)&f1Wi, (void*)&f1Wh,
                     (void*)&b0Wi, (void*)&b0Wh, (void*)&b1Wi, (void*)&b1Wh,
                     (void*)&f0bi, (void*)&f0bh, (void*)&f1bi, (void*)&f1bh,
                     (void*)&b0bi, (void*)&b0bh, (void*)&b1bi, (void*)&b1bh,
                     (void*)&Hhi, (void*)&Hlo, (void*)&part, (void*)&cnt, (void*)&Hfin };
    hipLaunchCooperativeKernel((void*)rnn_persist, dim3(224), dim3(512),
                               args, 0, stream);

    fc1_kernel<<<128, 64, 0, stream>>>(fc1W, fc1b, Hfin, fc1out);
    fc2_kernel<<<1, 256, 0, stream>>>(fc2W, fc2b, fc1out, out);
}

// Round 8
// 12982.010 us; speedup vs baseline: 2.3701x; 1.2478x over previous
//
#include <hip/hip_runtime.h>

// BiRNN: B=128, S=512, E=512, H=1024, V=50000, C=2
// Persistent cooperative kernel, 224 blocks (1/CU), split-K layout:
//   h0 tiles: 8 stripes x 6 K-chunks (2 egather + 4 recurrent), per dir
//   h1 tiles: 8 stripes x 8 K-chunks, per dir
// Weights LDS-resident (bf16 hi/lo, frag order). A staged through 16KB LDS
// with a 3-deep register prefetch pipeline (covers LLC latency).
// ALL cross-phase state via relaxed agent-scope atomics (sc1 -> LLC), no
// cache-maintenance fences. Two-level last-arriver barrier + flag, 2/phase.

#define S_LEN 512

typedef short bf16x8 __attribute__((ext_vector_type(8)));
typedef float f32x4 __attribute__((ext_vector_type(4)));

__device__ __forceinline__ unsigned short f2bf(float f) {
    unsigned u = __float_as_uint(f);
    u += 0x7fff + ((u >> 16) & 1);
    return (unsigned short)(u >> 16);
}
__device__ __forceinline__ float bf2f(unsigned short h) {
    return __uint_as_float(((unsigned)h) << 16);
}
__device__ __forceinline__ f32x4 mfma16(bf16x8 a, bf16x8 b, f32x4 c) {
    return __builtin_amdgcn_mfma_f32_16x16x32_bf16(a, b, c, 0, 0, 0);
}
// relaxed agent-scope (sc1, coherence-point) accesses
__device__ __forceinline__ unsigned long long ld8_cc(const void* p) {
    return __hip_atomic_load((unsigned long long*)p, __ATOMIC_RELAXED,
                             __HIP_MEMORY_SCOPE_AGENT);
}
__device__ __forceinline__ void st8_cc(void* p, unsigned long long v) {
    __hip_atomic_store((unsigned long long*)p, v, __ATOMIC_RELAXED,
                       __HIP_MEMORY_SCOPE_AGENT);
}
__device__ __forceinline__ void st4_cc(void* p, float v) {
    __hip_atomic_store((int*)p, __float_as_int(v), __ATOMIC_RELAXED,
                       __HIP_MEMORY_SCOPE_AGENT);
}

union U8  { unsigned long long u; float f[2]; unsigned short s[4]; };
union F16 { bf16x8 v; unsigned long long u[2]; unsigned short s[8]; };

// ws layout (bytes):
//  part @ 0          : [32 tile][8 chunk][128][128] f32 = 16,777,216
//  Hhi  @ 16,777,216 : 8 slices x 131072 ushort = 2,097,152
//  Hlo  @ 18,874,368 : 2,097,152
//  Hfin @ 20,971,520 : [2 dir][128][1024] f32 = 1,048,576
//  cnt  @ 22,020,096 : 8 counters x 64B = 512
//  l2c  @ 22,020,608 : 64B
//  flag @ 22,020,672 : 64B
//  fc1  @ 22,024,192 : 32,768

// two-level last-arriver barrier (all counters monotonic; cumulative targets):
// arrival -> cnt[bid&7]; its 28th arrival of this epoch -> l2c; l2c's 8th
// -> flag = ep. Everyone spins read-only on flag.
__device__ __forceinline__ void gbar(int* cnt, int* l2c, int* flag,
                                     int bid, int tid, int ep) {
    __syncthreads();   // drains each wave's vmcnt -> all sc1 stores LLC-acked
    if (tid == 0) {
        int old = __hip_atomic_fetch_add(cnt + (bid & 7) * 16, 1,
                                         __ATOMIC_RELAXED, __HIP_MEMORY_SCOPE_AGENT);
        if (old == ep * 28 - 1) {
            int old2 = __hip_atomic_fetch_add(l2c, 1, __ATOMIC_RELAXED,
                                              __HIP_MEMORY_SCOPE_AGENT);
            if (old2 == ep * 8 - 1)
                __hip_atomic_store(flag, ep, __ATOMIC_RELAXED,
                                   __HIP_MEMORY_SCOPE_AGENT);
        }
        while (__hip_atomic_load(flag, __ATOMIC_RELAXED,
                                 __HIP_MEMORY_SCOPE_AGENT) < ep)
            __builtin_amdgcn_s_sleep(1);
    }
    __syncthreads();
}

__global__ __launch_bounds__(512) void rnn_persist(
    const int* __restrict__ x, const float* __restrict__ emb,
    const float* __restrict__ f0Wi, const float* __restrict__ f0Wh,
    const float* __restrict__ f1Wi, const float* __restrict__ f1Wh,
    const float* __restrict__ b0Wi, const float* __restrict__ b0Wh,
    const float* __restrict__ b1Wi, const float* __restrict__ b1Wh,
    const float* __restrict__ f0bi, const float* __restrict__ f0bh,
    const float* __restrict__ f1bi, const float* __restrict__ f1bh,
    const float* __restrict__ b0bi, const float* __restrict__ b0bh,
    const float* __restrict__ b1bi, const float* __restrict__ b1bh,
    unsigned short* __restrict__ Hhi, unsigned short* __restrict__ Hlo,
    float* __restrict__ part, int* __restrict__ cnt, int* __restrict__ l2c,
    int* __restrict__ flag, float* __restrict__ Hfin)
{
    // LDS: [0,32768) W-hi  [32768,65536) W-lo  (frag order, tile k x 128 cols)
    //      [65536,69632) A-stage hi  [69632,73728) A-stage lo   (128 rows x 32 k)
    __shared__ unsigned short lds[73728];   // 144 KiB

    const int bid = blockIdx.x, tid = threadIdx.x;
    const int dir = bid / 112;
    const int rr = bid % 112;
    int stripe, chunk;
    if (rr < 48) { stripe = rr / 6; chunk = rr % 6; }
    else         { int r2 = rr - 48; stripe = 8 + (r2 >> 3); chunk = r2 & 7; }
    const bool isH0 = stripe < 8;
    const bool eg = isH0 && (chunk < 2);
    const int nparts = isH0 ? 6 : 8;
    const int cstart = (stripe & 7) * 128;
    const int tile = dir * 16 + stripe;
    const int hout = isH0 ? 0 : 1;

    // weight source + k-offset within that matrix
    const float* Wsrc; int koffw; int hselA = 0;
    if (isH0) {
        if (eg) { Wsrc = dir ? b0Wi : f0Wi; koffw = chunk * 256; }
        else    { Wsrc = dir ? b0Wh : f0Wh; koffw = chunk * 256 - 512; }
    } else {
        if (chunk < 4) { Wsrc = dir ? b1Wi : f1Wi; koffw = chunk * 256;        hselA = 0; }
        else           { Wsrc = dir ? b1Wh : f1Wh; koffw = chunk * 256 - 1024; hselA = 1; }
    }
    const float *bA, *bB;
    if (isH0) { bA = dir ? b0bi : f0bi; bB = dir ? b0bh : f0bh; }
    else      { bA = dir ? b1bi : f1bi; bB = dir ? b1bh : f1bh; }

    // ---- one-time: weight tile -> LDS (hi/lo, frag order) ----
    for (int q = tid; q < 32768; q += 512) {
        int k = q >> 7, c = q & 127;
        float w = Wsrc[(size_t)(koffw + k) * 1024 + cstart + c];
        unsigned short h = f2bf(w);
        int o = ((k >> 3) * 128 + c) * 8 + (k & 7);
        lds[o] = h;
        lds[32768 + o] = f2bf(w - bf2f(h));
    }

    const int lane = tid & 63, wid = tid >> 6;
    const int wm = (wid >> 2) * 64, wn = (wid & 3) * 32;
    const int lrow = lane & 15, kgrp = lane >> 4;
    const int srow = tid >> 2;          // stager row 0..127
    const int skq  = tid & 3;           // stager k-quarter
    const int sk   = skq * 8;           // k-elem offset within 32-k step

    float* myPart = part + (size_t)(tile * 8 + chunk) * 16384;
    const float* pb = part + (size_t)tile * 8 * 16384;
    const int r0 = (chunk * 128) / nparts, r1 = ((chunk + 1) * 128) / nparts;

#define ISSUE(sl, sv)                                                          \
    do { if (eg) {                                                             \
            const float* ep_ = erow + (sv) * 32;                               \
            e0[sl] = *(const float4*)(ep_); e1[sl] = *(const float4*)(ep_ + 4);\
        } else {                                                               \
            gh[sl].u[0] = ld8_cc(ahB + (sv) * 32);                             \
            gh[sl].u[1] = ld8_cc(ahB + (sv) * 32 + 4);                         \
            gl[sl].u[0] = ld8_cc(alB + (sv) * 32);                             \
            gl[sl].u[1] = ld8_cc(alB + (sv) * 32 + 4);                         \
        } } while (0)

#define STAGE(sl)                                                              \
    do { int ao_ = (skq * 128 + srow) * 8;                                     \
        if (eg) {                                                              \
            F16 hh_, ll_;                                                      \
            float ev_[8] = {e0[sl].x, e0[sl].y, e0[sl].z, e0[sl].w,            \
                            e1[sl].x, e1[sl].y, e1[sl].z, e1[sl].w};           \
            _Pragma("unroll") for (int j_ = 0; j_ < 8; ++j_) {                 \
                unsigned short h_ = f2bf(ev_[j_]);                             \
                hh_.s[j_] = h_; ll_.s[j_] = f2bf(ev_[j_] - bf2f(h_)); }        \
            *(bf16x8*)&lds[65536 + ao_] = hh_.v;                               \
            *(bf16x8*)&lds[69632 + ao_] = ll_.v;                               \
        } else {                                                               \
            *(bf16x8*)&lds[65536 + ao_] = gh[sl].v;                            \
            *(bf16x8*)&lds[69632 + ao_] = gl[sl].v; } } while (0)

#define CONSUME(sv)                                                            \
    do { bf16x8 bh_[2], bl_[2];                                                \
        _Pragma("unroll") for (int jj_ = 0; jj_ < 2; ++jj_) {                  \
            int bo_ = (((sv) * 4 + kgrp) * 128 + wn + jj_ * 16 + lrow) * 8;    \
            bh_[jj_] = *(const bf16x8*)&lds[bo_];                              \
            bl_[jj_] = *(const bf16x8*)&lds[32768 + bo_]; }                    \
        _Pragma("unroll") for (int i_ = 0; i_ < 4; ++i_) {                     \
            int ao_ = (kgrp * 128 + wm + i_ * 16 + lrow) * 8;                  \
            bf16x8 ah_ = *(const bf16x8*)&lds[65536 + ao_];                    \
            bf16x8 al_ = *(const bf16x8*)&lds[69632 + ao_];                    \
            _Pragma("unroll") for (int jj_ = 0; jj_ < 2; ++jj_) {              \
                acc[i_][jj_] = mfma16(ah_, bh_[jj_], acc[i_][jj_]);            \
                acc[i_][jj_] = mfma16(ah_, bl_[jj_], acc[i_][jj_]);            \
                acc[i_][jj_] = mfma16(al_, bh_[jj_], acc[i_][jj_]); } } } while (0)

#define REDUCE(NP)                                                             \
    do { for (int u = tid; u < nrows * 32; u += 512) {                         \
            int row = r0 + (u >> 5), cq = (u & 31) * 4;                        \
            int off = row * 128 + cq;                                          \
            U8 a0, a1;                                                         \
            a0.u = ld8_cc(pb + off); a1.u = ld8_cc(pb + off + 2);              \
            float s0 = a0.f[0], s1 = a0.f[1], s2 = a1.f[0], s3 = a1.f[1];      \
            _Pragma("unroll") for (int q = 1; q < (NP); ++q) {                 \
                const float* pq = pb + (size_t)q * 16384 + off;                \
                a0.u = ld8_cc(pq); a1.u = ld8_cc(pq + 2);                      \
                s0 += a0.f[0]; s1 += a0.f[1]; s2 += a1.f[0]; s3 += a1.f[1]; }  \
            int gc = cstart + cq;                                              \
            s0 = tanhf(s0 + bA[gc]     + bB[gc]);                              \
            s1 = tanhf(s1 + bA[gc + 1] + bB[gc + 1]);                          \
            s2 = tanhf(s2 + bA[gc + 2] + bB[gc + 2]);                          \
            s3 = tanhf(s3 + bA[gc + 3] + bB[gc + 3]);                          \
            U8 hu, lu;                                                         \
            unsigned short h0 = f2bf(s0), h1 = f2bf(s1);                       \
            unsigned short h2 = f2bf(s2), h3 = f2bf(s3);                       \
            hu.s[0] = h0; hu.s[1] = h1; hu.s[2] = h2; hu.s[3] = h3;            \
            lu.s[0] = f2bf(s0 - bf2f(h0)); lu.s[1] = f2bf(s1 - bf2f(h1));      \
            lu.s[2] = f2bf(s2 - bf2f(h2)); lu.s[3] = f2bf(s3 - bf2f(h3));      \
            size_t ho = (size_t)row * 1024 + gc;                               \
            st8_cc(dh + ho, hu.u);                                             \
            st8_cc(dl + ho, lu.u);                                             \
            if (fin) {                                                         \
                float* fo = Hfin + (size_t)dir * 131072 + row * 1024 + gc;     \
                st4_cc(fo, s0); st4_cc(fo + 1, s1);                            \
                st4_cc(fo + 2, s2); st4_cc(fo + 3, s3);                        \
            } } } while (0)

    int ep = 0;
    for (int p = 0; p <= S_LEN; ++p) {
        const bool act = isH0 ? (p < S_LEN) : (p > 0);
        const int rp = (p + 1) & 1, wp = p & 1;

        if (act) {
            // ---- GEMM: 128x128 tile over this block's 256-k chunk ----
            const unsigned short* ahB = Hhi;
            const unsigned short* alB = Hlo;
            const float* erow = emb;
            if (eg) {
                int tsel = dir ? (S_LEN - 1 - p) : p;
                int idx = x[srow * S_LEN + tsel];
                erow = emb + (size_t)idx * 512 + koffw + sk;
            } else {
                size_t hb = (size_t)((hselA * 2 + dir) * 2 + rp) * 131072
                          + (size_t)srow * 1024 + koffw + sk;
                ahB = Hhi + hb;
                alB = Hlo + hb;
            }

            f32x4 acc[4][2];
            #pragma unroll
            for (int i = 0; i < 4; ++i)
                #pragma unroll
                for (int j = 0; j < 2; ++j) acc[i][j] = (f32x4){0.f, 0.f, 0.f, 0.f};

            float4 e0[3], e1[3];
            F16 gh[3], gl[3];
            ISSUE(0, 0); ISSUE(1, 1); ISSUE(2, 2);
            #pragma unroll
            for (int s = 0; s < 8; ++s) {
                const int sl = s % 3;               // static under full unroll
                __syncthreads();                    // consumers of step s-1 done
                STAGE(sl);                          // waits only on step-s loads
                __syncthreads();                    // stage visible
                if (s < 5) ISSUE(sl, s + 3);        // refill freed set, 3 ahead
                CONSUME(s);
            }

            // partial store (sc1, 4B)
            #pragma unroll
            for (int i = 0; i < 4; ++i)
                #pragma unroll
                for (int jj = 0; jj < 2; ++jj) {
                    int col = wn + jj * 16 + lrow;
                    #pragma unroll
                    for (int r4 = 0; r4 < 4; ++r4) {
                        int row = wm + i * 16 + kgrp * 4 + r4;
                        st4_cc(myPart + row * 128 + col, acc[i][jj][r4]);
                    }
                }
        }

        ++ep; gbar(cnt, l2c, flag, bid, tid, ep);

        if (act) {
            // ---- reduce own row-slice of own tile + bias + tanh + h store ----
            unsigned short* dh = Hhi + (size_t)((hout * 2 + dir) * 2 + wp) * 131072;
            unsigned short* dl = Hlo + (size_t)((hout * 2 + dir) * 2 + wp) * 131072;
            const bool fin = (!isH0) && (p == S_LEN);
            const int nrows = r1 - r0;
            if (isH0) REDUCE(6); else REDUCE(8);
        }

        ++ep; gbar(cnt, l2c, flag, bid, tid, ep);
    }
#undef ISSUE
#undef STAGE
#undef CONSUME
#undef REDUCE
}

// ---------------------------------------------------------------------------
// Epilogue: out = (concat(h_fwd, h_bwd) @ fc1 + b1) @ fc2 + b2
// ---------------------------------------------------------------------------
__global__ __launch_bounds__(64) void fc1_kernel(
    const float* __restrict__ fc1W, const float* __restrict__ fc1b,
    const float* __restrict__ Hfin, float* __restrict__ fc1out)
{
    int r = blockIdx.x;      // 0..127
    int c = threadIdx.x;     // 0..63
    const float* hf = Hfin + (size_t)r * 1024;
    const float* hb = Hfin + 131072 + (size_t)r * 1024;
    float s = fc1b[c];
    for (int k = 0; k < 1024; ++k) s += hf[k] * fc1W[k * 64 + c];
    for (int k = 0; k < 1024; ++k) s += hb[k] * fc1W[(1024 + k) * 64 + c];
    fc1out[r * 64 + c] = s;
}

__global__ __launch_bounds__(256) void fc2_kernel(
    const float* __restrict__ fc2W, const float* __restrict__ fc2b,
    const float* __restrict__ fc1out, float* __restrict__ out)
{
    int tid = threadIdx.x;   // 128 rows x 2 cols
    int r = tid >> 1, c = tid & 1;
    const float* f = fc1out + r * 64;
    float s = fc2b[c];
    for (int k = 0; k < 64; ++k) s += f[k] * fc2W[k * 2 + c];
    out[r * 2 + c] = s;
}

extern "C" void kernel_launch(void* const* d_in, const int* in_sizes, int n_in,
                              void* d_out, int out_size, void* d_ws, size_t ws_size,
                              hipStream_t stream)
{
    const int*   x    = (const int*)d_in[0];
    const float* emb  = (const float*)d_in[1];
    const float* f0Wi = (const float*)d_in[2];
    const float* f0bi = (const float*)d_in[3];
    const float* f0Wh = (const float*)d_in[4];
    const float* f0bh = (const float*)d_in[5];
    const float* f1Wi = (const float*)d_in[6];
    const float* f1bi = (const float*)d_in[7];
    const float* f1Wh = (const float*)d_in[8];
    const float* f1bh = (const float*)d_in[9];
    const float* b0Wi = (const float*)d_in[10];
    const float* b0bi = (const float*)d_in[11];
    const float* b0Wh = (const float*)d_in[12];
    const float* b0bh = (const float*)d_in[13];
    const float* b1Wi = (const float*)d_in[14];
    const float* b1bi = (const float*)d_in[15];
    const float* b1Wh = (const float*)d_in[16];
    const float* b1bh = (const float*)d_in[17];
    const float* fc1W = (const float*)d_in[18];
    const float* fc1b = (const float*)d_in[19];
    const float* fc2W = (const float*)d_in[20];
    const float* fc2b = (const float*)d_in[21];
    float* out = (float*)d_out;

    char* wsb = (char*)d_ws;
    float*          part = (float*)(wsb);
    unsigned short* Hhi  = (unsigned short*)(wsb + 16777216);
    unsigned short* Hlo  = (unsigned short*)(wsb + 18874368);
    float*          Hfin = (float*)(wsb + 20971520);
    int*            cnt  = (int*)(wsb + 22020096);
    int*            l2c  = (int*)(wsb + 22020608);
    int*            flag = (int*)(wsb + 22020672);
    float*          fc1out = (float*)(wsb + 22024192);

    // zero h state (both parities, hi+lo), barrier counters, l2c, flag
    hipMemsetAsync(wsb + 16777216, 0, 4194304, stream);
    hipMemsetAsync(wsb + 22020096, 0, 1024, stream);

    void* args[] = { (void*)&x, (void*)&emb,
                     (void*)&f0Wi, (void*)&f0Wh, (void*)&f1Wi, (void*)&f1Wh,
                     (void*)&b0Wi, (void*)&b0Wh, (void*)&b1Wi, (void*)&b1Wh,
                     (void*)&f0bi, (void*)&f0bh, (void*)&f1bi, (void*)&f1bh,
                     (void*)&b0bi, (void*)&b0bh, (void*)&b1bi, (void*)&b1bh,
                     (void*)&Hhi, (void*)&Hlo, (void*)&part, (void*)&cnt,
                     (void*)&l2c, (void*)&flag, (void*)&Hfin };
    hipLaunchCooperativeKernel((void*)rnn_persist, dim3(224), dim3(512),
                               args, 0, stream);

    fc1_kernel<<<128, 64, 0, stream>>>(fc1W, fc1b, Hfin, fc1out);
    fc2_kernel<<<1, 256, 0, stream>>>(fc2W, fc2b, fc1out, out);
}